// Round 3
// baseline (1747.337 us; speedup 1.0000x reference)
//
#include <hip/hip_runtime.h>
#include <hip/hip_bf16.h>
#include <cstdint>
#include <cstddef>

#define D_DIM 128
#define NEG_LOG2E (-1.44269504f)

typedef __attribute__((ext_vector_type(8))) short short8;
typedef __attribute__((ext_vector_type(4))) float f32x4;

__device__ __forceinline__ float sigmoid_fast(float z) {
  return __builtin_amdgcn_rcpf(1.0f + __expf(-z));
}

__device__ __forceinline__ unsigned short f2bf(float f) {
  union { float f; unsigned u; } v; v.f = f;
  unsigned r = v.u + 0x7FFF + ((v.u >> 16) & 1);   // RNE
  return (unsigned short)(r >> 16);
}
__device__ __forceinline__ float bf_lo(unsigned u) { return __uint_as_float(u << 16); }
__device__ __forceinline__ float bf_hi(unsigned u) { return __uint_as_float(u & 0xFFFF0000u); }

// Fused: wconv (blocks 0..95) + coarse histogram (all blocks) + bucket scan
// (performed by the last block to finish, via device-scope done-counter).
// Buckets: 64 dsts each for BOTH node types. NB <= 2048.
__global__ __launch_bounds__(256) void fused_pre_kernel(
    const float* __restrict__ s0, const float* __restrict__ s1, const float* __restrict__ s2,
    const float* __restrict__ s3, const float* __restrict__ s4, const float* __restrict__ s5,
    short* __restrict__ wdst,
    const int* __restrict__ dst_dt, const int* __restrict__ dst_td,
    int* __restrict__ ghist, int* __restrict__ done,
    int* __restrict__ bbase, int* __restrict__ bcur,
    int nbt, int NB, int E) {
  __shared__ int lh[2048];
  __shared__ int sc[256];
  __shared__ int lastflag;
  int t = threadIdx.x;

  // --- weight bf16 conversion (6 x 128x128 matrices) ---
  if (blockIdx.x < 96) {
    int idx = blockIdx.x * 256 + t;
    int mat = idx >> 12;
    int pos = (idx & 4095) * 4;
    const float* s = (mat == 0) ? s0 : (mat == 1) ? s1 : (mat == 2) ? s2
                   : (mat == 3) ? s3 : (mat == 4) ? s4 : s5;
    float4 f = *(const float4*)(s + pos);
    short4 o;
    o.x = (short)f2bf(f.x); o.y = (short)f2bf(f.y);
    o.z = (short)f2bf(f.z); o.w = (short)f2bf(f.w);
    *(short4*)(wdst + mat * 16384 + pos) = o;
  }

  // --- coarse histogram with LDS pre-aggregation ---
#pragma unroll
  for (int k = 0; k < 8; ++k) lh[t + k * 256] = 0;
  __syncthreads();
  for (int i = blockIdx.x * 256 + t; i < E; i += gridDim.x * 256) {
    atomicAdd(&lh[dst_dt[i] >> 6], 1);
    atomicAdd(&lh[nbt + (dst_td[i] >> 6)], 1);
  }
  __syncthreads();
#pragma unroll
  for (int k = 0; k < 8; ++k) {
    int b = t + k * 256;
    int c = lh[b];
    if (b < NB && c) atomicAdd(&ghist[b], c);
  }
  __threadfence();
  __syncthreads();
  if (t == 0) {
    int prev = atomicAdd(done, 1);
    lastflag = (prev == (int)gridDim.x - 1);
  }
  __syncthreads();
  if (!lastflag) return;
  __threadfence();

  // --- bucket scan (single block, 8 buckets/thread) ---
  int i0 = t * 8;
  int c[8]; int s = 0;
#pragma unroll
  for (int k = 0; k < 8; ++k) {
    c[k] = (i0 + k < NB) ? atomicAdd(&ghist[i0 + k], 0) : 0;
    s += c[k];
  }
  sc[t] = s; __syncthreads();
  for (int st = 1; st < 256; st <<= 1) {
    int u = (t >= st) ? sc[t - st] : 0;
    __syncthreads(); sc[t] += u; __syncthreads();
  }
  int base = sc[t] - s;
#pragma unroll
  for (int k = 0; k < 8; ++k) {
    if (i0 + k < NB) { bbase[i0 + k] = base; bcur[i0 + k] = base; base += c[k]; }
  }
  if (t == 255) bbase[NB] = sc[255];
}

// Per-node MFMA precompute for BOTH node types in one launch.
// G channel of YG is pre-scaled by -log2e so gather's sigmoid uses exp2 directly.
__global__ __launch_bounds__(256) void node_mfma_all(
    const float* __restrict__ x_data, const float* __restrict__ x_task,
    const short* __restrict__ Wb,
    const float* __restrict__ bmn_dt, const float* __restrict__ bme_dt,
    const float* __restrict__ bgn_dt, const float* __restrict__ bge_dt,
    const float* __restrict__ bmn_td, const float* __restrict__ bme_td,
    const float* __restrict__ bgn_td, const float* __restrict__ bge_td,
    const float* __restrict__ bs_data, const float* __restrict__ bs_task,
    const float* __restrict__ bias_dt, const float* __restrict__ bias_td,
    unsigned int* __restrict__ YG_dt, unsigned int* __restrict__ YG_td,
    float* __restrict__ out, int n_data, int n_task, int gd) {
  __shared__ unsigned sh[32][132];
  const bool is_data = (int)blockIdx.x < gd;
  const float* x; const short *Wmnb, *Wgnb, *Wsb;
  const float *bmn, *bme, *bgn, *bge, *bs, *bias_other;
  unsigned* YG; float* out_init; int n, bid;
  if (is_data) {
    x = x_data; Wmnb = Wb; Wgnb = Wb + 16384; Wsb = Wb + 32768;
    bmn = bmn_dt; bme = bme_dt; bgn = bgn_dt; bge = bge_dt;
    bs = bs_data; bias_other = bias_td;
    YG = YG_dt; out_init = out; n = n_data; bid = blockIdx.x;
  } else {
    x = x_task; Wmnb = Wb + 3 * 16384; Wgnb = Wb + 4 * 16384; Wsb = Wb + 5 * 16384;
    bmn = bmn_td; bme = bme_td; bgn = bgn_td; bge = bge_td;
    bs = bs_task; bias_other = bias_dt;
    YG = YG_td; out_init = out + (size_t)n_data * D_DIM; n = n_task; bid = blockIdx.x - gd;
  }
  const int t = threadIdx.x;
  const int wave = t >> 6, lane = t & 63;
  const int q = lane >> 4, l15 = lane & 15;
  const int ng = wave >> 1;
  const int h = (wave & 1) * 64;
  const int base_node = bid * 32;
  const int node_base = base_node + ng * 16;

  short8 a[4];
  {
    int m = node_base + l15;
    int mc = m < n ? m : (n - 1);
    const float* xrow = x + (size_t)mc * D_DIM;
#pragma unroll
    for (int ks = 0; ks < 4; ++ks) {
      float4 f0 = *(const float4*)(xrow + ks * 32 + q * 8);
      float4 f1 = *(const float4*)(xrow + ks * 32 + q * 8 + 4);
      union { short8 s; __hip_bfloat162 hh[4]; } u;
      u.hh[0] = __float22bfloat162_rn({f0.x, f0.y});
      u.hh[1] = __float22bfloat162_rn({f0.z, f0.w});
      u.hh[2] = __float22bfloat162_rn({f1.x, f1.y});
      u.hh[3] = __float22bfloat162_rn({f1.z, f1.w});
      a[ks] = u.s;
    }
  }

  f32x4 accY[4], accG[4], accS[4];
#pragma unroll
  for (int nt = 0; nt < 4; ++nt) { accY[nt] = {0,0,0,0}; accG[nt] = {0,0,0,0}; accS[nt] = {0,0,0,0}; }

#pragma unroll
  for (int nt = 0; nt < 4; ++nt) {
    const int row = h + nt * 16 + l15;
#pragma unroll
    for (int ks = 0; ks < 4; ++ks) {
      const int off = row * D_DIM + ks * 32 + q * 8;
      short8 bm  = *(const short8*)(Wmnb + off);
      short8 bg  = *(const short8*)(Wgnb + off);
      short8 bsw = *(const short8*)(Wsb + off);
      accY[nt] = __builtin_amdgcn_mfma_f32_16x16x32_bf16(a[ks], bm,  accY[nt], 0, 0, 0);
      accG[nt] = __builtin_amdgcn_mfma_f32_16x16x32_bf16(a[ks], bg,  accG[nt], 0, 0, 0);
      accS[nt] = __builtin_amdgcn_mfma_f32_16x16x32_bf16(a[ks], bsw, accS[nt], 0, 0, 0);
    }
  }

#pragma unroll
  for (int nt = 0; nt < 4; ++nt) {
    int d = h + nt * 16 + l15;
    float bmv = bmn[d] + bme[d];
    float bgv = bgn[d] + bge[d];
#pragma unroll
    for (int r = 0; r < 4; ++r) {
      union { __hip_bfloat162 hh; unsigned u; } pck;
      pck.hh = __float22bfloat162_rn({accY[nt][r] + bmv,
                                      (accG[nt][r] + bgv) * NEG_LOG2E});
      sh[ng * 16 + q * 4 + r][d] = pck.u;
    }
  }
  __syncthreads();
#pragma unroll
  for (int it = 0; it < 4; ++it) {
    int idx = (it * 256 + t) * 4;
    int nl = idx >> 7, dd = idx & 127;
    int node = base_node + nl;
    if (node < n)
      *(uint4*)(YG + (size_t)node * D_DIM + dd) = *(const uint4*)&sh[nl][dd];
  }
  __syncthreads();

  float* shf = (float*)sh;
#pragma unroll
  for (int nt = 0; nt < 4; ++nt) {
    int d = h + nt * 16 + l15;
    float bsv = bs[d];
#pragma unroll
    for (int r = 0; r < 4; ++r)
      shf[(ng * 16 + q * 4 + r) * 132 + d] = sigmoid_fast(accS[nt][r] + bsv) + 0.5f;
  }
  __syncthreads();
#pragma unroll
  for (int it = 0; it < 4; ++it) {
    int idx = (it * 256 + t) * 4;
    int nl = idx >> 7, dd = idx & 127;
    int node = base_node + nl;
    if (node < n) {
      float4 xv = *(const float4*)(x + (size_t)node * D_DIM + dd);
      float4 bo = *(const float4*)(bias_other + dd);
      const float* sp = &shf[nl * 132 + dd];
      float4 o;
      o.x = sp[0] * xv.x + bo.x;
      o.y = sp[1] * xv.y + bo.y;
      o.z = sp[2] * xv.z + bo.z;
      o.w = sp[3] * xv.w + bo.w;
      *(float4*)(out_init + (size_t)node * D_DIM + dd) = o;
    }
  }
}

// Single partition pass: block handles 4096 edges of each list; per-bucket
// contiguous runs reserved with one global atomicAdd. Entry = {src, ef_hi24|loc6}.
__global__ __launch_bounds__(256) void sort_a_kernel(
    const int* __restrict__ src_dt, const int* __restrict__ dst_dt, const float* __restrict__ ef_dt,
    const int* __restrict__ src_td, const int* __restrict__ dst_td, const float* __restrict__ ef_td,
    int* __restrict__ bcur, int2* __restrict__ eA, int nbt, int NB, int E) {
  __shared__ int lh[2048];
  __shared__ int lcur[2048];
  int t = threadIdx.x;
#pragma unroll
  for (int k = 0; k < 8; ++k) lh[t + k * 256] = 0;
  __syncthreads();
  int e0 = blockIdx.x * 4096;
  int e1 = min(E, e0 + 4096);
  for (int i = e0 + t; i < e1; i += 256) {
    atomicAdd(&lh[dst_dt[i] >> 6], 1);
    atomicAdd(&lh[nbt + (dst_td[i] >> 6)], 1);
  }
  __syncthreads();
#pragma unroll
  for (int k = 0; k < 8; ++k) {
    int b = t + k * 256;
    int c = lh[b];
    if (b < NB && c) lcur[b] = atomicAdd(&bcur[b], c);
  }
  __syncthreads();
  for (int i = e0 + t; i < e1; i += 256) {
    int c = dst_dt[i];
    int pos = atomicAdd(&lcur[c >> 6], 1);
    eA[pos] = make_int2(src_dt[i],
        (int)((__float_as_uint(ef_dt[i]) & 0xFFFFFF00u) | (unsigned)(c & 63)));
    int cd = dst_td[i];
    int pos2 = atomicAdd(&lcur[nbt + (cd >> 6)], 1);
    eA[pos2] = make_int2(src_td[i],
        (int)((__float_as_uint(ef_td[i]) & 0xFFFFFF00u) | (unsigned)(cd & 63)));
  }
}

// Bucket gather: one block per 64-dst bucket. Output rows staged in LDS
// (init = self-layer result already in out), unordered bucket edges streamed
// with 8 YG loads in flight per wave, messages accumulated via LDS atomics.
__global__ __launch_bounds__(256) void bucket_gather_kernel(
    const unsigned* __restrict__ YG_dt, const unsigned* __restrict__ YG_td,
    const int* __restrict__ bbase, const int2* __restrict__ eA,
    const float* __restrict__ Wme_dt, const float* __restrict__ Wge_dt,
    const float* __restrict__ Wme_td, const float* __restrict__ Wge_td,
    float* __restrict__ out, int nbt, int n_task, int n_data) {
  __shared__ float acc[64][D_DIM];          // 32 KB -> 5 blocks/CU
  const int b = blockIdx.x, t = threadIdx.x;
  const bool is_task = b < nbt;
  const unsigned* YG = is_task ? YG_dt : YG_td;
  const float* Wme = is_task ? Wme_dt : Wme_td;
  const float* Wge = is_task ? Wge_dt : Wge_td;
  int nloc; size_t orow0;
  if (is_task) { int c0 = b << 6; nloc = min(64, n_task - c0); orow0 = (size_t)(n_data + c0); }
  else         { int c0 = (b - nbt) << 6; nloc = min(64, n_data - c0); orow0 = (size_t)c0; }
  float* outp = out + orow0 * D_DIM;
  // stage init rows (contiguous) into LDS
  for (int i = t; i < (nloc << 5); i += 256) {
    int r = i >> 5, cI = (i & 31) << 2;
    *(float4*)&acc[r][cI] = *(const float4*)(outp + r * D_DIM + cI);
  }
  const int base = bbase[b], end = bbase[b + 1];
  const int lane = t & 63, wave = t >> 6;
  float2 wme = *(const float2*)(Wme + 2 * lane);
  float2 wge = *(const float2*)(Wge + 2 * lane);
  float2 wge2 = {wge.x * NEG_LOG2E, wge.y * NEG_LOG2E};
  __syncthreads();

  for (int p = base + (wave << 3); p < end; p += 32) {
    int lim = end - p; if (lim > 8) lim = 8;
    int2 e[8];
#pragma unroll
    for (int j = 0; j < 8; ++j) if (j < lim) e[j] = eA[p + j];
    uint2 yg[8];
#pragma unroll
    for (int j = 0; j < 8; ++j)
      if (j < lim) yg[j] = *(const uint2*)(YG + (size_t)e[j].x * D_DIM + 2 * lane);
#pragma unroll
    for (int j = 0; j < 8; ++j) if (j < lim) {
      float f = __int_as_float(e[j].y & (int)0xFFFFFF00);
      float g0 = __builtin_amdgcn_rcpf(1.0f + __builtin_amdgcn_exp2f(fmaf(f, wge2.x, bf_hi(yg[j].x)))) - 0.5f;
      float g1 = __builtin_amdgcn_rcpf(1.0f + __builtin_amdgcn_exp2f(fmaf(f, wge2.y, bf_hi(yg[j].y)))) - 0.5f;
      float m0 = fmaf(f, wme.x, bf_lo(yg[j].x)) * g0;
      float m1 = fmaf(f, wme.y, bf_lo(yg[j].y)) * g1;
      int loc = e[j].y & 63;
      atomicAdd(&acc[loc][2 * lane], m0);
      atomicAdd(&acc[loc][2 * lane + 1], m1);
    }
  }
  __syncthreads();
  // ReLU + writeback
  for (int i = t; i < (nloc << 5); i += 256) {
    int r = i >> 5, cI = (i & 31) << 2;
    float4 v = *(const float4*)&acc[r][cI];
    v.x = fmaxf(v.x, 0.0f); v.y = fmaxf(v.y, 0.0f);
    v.z = fmaxf(v.z, 0.0f); v.w = fmaxf(v.w, 0.0f);
    *(float4*)(outp + r * D_DIM + cI) = v;
  }
}

extern "C" void kernel_launch(void* const* d_in, const int* in_sizes, int n_in,
                              void* d_out, int out_size, void* d_ws, size_t ws_size,
                              hipStream_t stream) {
  const float* x_data  = (const float*)d_in[0];
  const float* x_task  = (const float*)d_in[1];
  const int*   src_dt  = (const int*)d_in[2];
  const int*   dst_dt  = (const int*)d_in[3];
  const float* ef_dt   = (const float*)d_in[4];
  const int*   src_td  = (const int*)d_in[5];
  const int*   dst_td  = (const int*)d_in[6];
  const float* ef_td   = (const float*)d_in[7];
  const float* Wmn_dt  = (const float*)d_in[8];
  const float* bmn_dt  = (const float*)d_in[9];
  const float* Wme_dt  = (const float*)d_in[10];
  const float* bme_dt  = (const float*)d_in[11];
  const float* Wgn_dt  = (const float*)d_in[12];
  const float* bgn_dt  = (const float*)d_in[13];
  const float* Wge_dt  = (const float*)d_in[14];
  const float* bge_dt  = (const float*)d_in[15];
  const float* bias_dt = (const float*)d_in[16];
  const float* Wmn_td  = (const float*)d_in[17];
  const float* bmn_td  = (const float*)d_in[18];
  const float* Wme_td  = (const float*)d_in[19];
  const float* bme_td  = (const float*)d_in[20];
  const float* Wgn_td  = (const float*)d_in[21];
  const float* bgn_td  = (const float*)d_in[22];
  const float* Wge_td  = (const float*)d_in[23];
  const float* bge_td  = (const float*)d_in[24];
  const float* bias_td = (const float*)d_in[25];
  const float* Ws_data = (const float*)d_in[26];
  const float* bs_data = (const float*)d_in[27];
  const float* Ws_task = (const float*)d_in[28];
  const float* bs_task = (const float*)d_in[29];
  float* out = (float*)d_out;

  const int N_DATA = in_sizes[0] / D_DIM;   // 100000
  const int N_TASK = in_sizes[1] / D_DIM;   // 20000
  const int E = in_sizes[2];                // 1000000
  const int NBT = (N_TASK + 63) >> 6;       // 313 task buckets (64 dsts each)
  const int NBD = (N_DATA + 63) >> 6;       // 1563 data buckets (64 dsts each)
  const int NB = NBT + NBD;                 // 1876 (<= 2048)
  const int GD = (N_DATA + 31) / 32;
  const int GT = (N_TASK + 31) / 32;

  char* ws = (char*)d_ws;
  size_t off = 0;
  auto alloc = [&](size_t bytes) { void* p = ws + off; off += (bytes + 255) & ~(size_t)255; return p; };
  unsigned int* YG_dt = (unsigned int*)alloc((size_t)N_DATA * D_DIM * 4);
  unsigned int* YG_td = (unsigned int*)alloc((size_t)N_TASK * D_DIM * 4);
  int2* eA     = (int2*)alloc((size_t)2 * E * 8);
  int*  ghist  = (int*)alloc(2560 * 4);     // 2048 hist + done counter @2048
  int*  bbase  = (int*)alloc(2304 * 4);
  int*  bcur   = (int*)alloc(2304 * 4);
  short* Wb    = (short*)alloc((size_t)6 * 16384 * 2);
  (void)ws_size; (void)n_in; (void)out_size;

  hipMemsetAsync(ghist, 0, 2560 * 4, stream);

  fused_pre_kernel<<<256, 256, 0, stream>>>(
      Wmn_dt, Wgn_dt, Ws_data, Wmn_td, Wgn_td, Ws_task, Wb,
      dst_dt, dst_td, ghist, ghist + 2048, bbase, bcur,
      NBT, NB, E);

  node_mfma_all<<<GD + GT, 256, 0, stream>>>(
      x_data, x_task, Wb,
      bmn_dt, bme_dt, bgn_dt, bge_dt,
      bmn_td, bme_td, bgn_td, bge_td,
      bs_data, bs_task, bias_dt, bias_td,
      YG_dt, YG_td, out, N_DATA, N_TASK, GD);

  sort_a_kernel<<<(E + 4095) / 4096, 256, 0, stream>>>(
      src_dt, dst_dt, ef_dt, src_td, dst_td, ef_td, bcur, eA, NBT, NB, E);

  bucket_gather_kernel<<<NB, 256, 0, stream>>>(
      YG_dt, YG_td, bbase, eA, Wme_dt, Wge_dt, Wme_td, Wge_td,
      out, NBT, N_TASK, N_DATA);
}

// Round 5
// 1739.147 us; speedup vs baseline: 1.0047x; 1.0047x over previous
//
#include <hip/hip_runtime.h>
#include <hip/hip_bf16.h>
#include <cstdint>
#include <cstddef>

#define D_DIM 128
#define NEG_LOG2E (-1.44269504f)

typedef __attribute__((ext_vector_type(8))) short short8;
typedef __attribute__((ext_vector_type(4))) float f32x4;

__device__ __forceinline__ float sigmoid_fast(float z) {
  return __builtin_amdgcn_rcpf(1.0f + __expf(-z));
}

__device__ __forceinline__ unsigned short f2bf(float f) {
  union { float f; unsigned u; } v; v.f = f;
  unsigned r = v.u + 0x7FFF + ((v.u >> 16) & 1);   // RNE
  return (unsigned short)(r >> 16);
}
__device__ __forceinline__ float bf_lo(unsigned u) { return __uint_as_float(u << 16); }
__device__ __forceinline__ float bf_hi(unsigned u) { return __uint_as_float(u & 0xFFFF0000u); }

// Fused: wconv (blocks 0..95) + coarse histogram (all blocks) + bucket scan
// (performed by the last block to finish, via device-scope done-counter).
// Buckets: 64 dsts each for BOTH node types. NB <= 2048.
__global__ __launch_bounds__(256) void fused_pre_kernel(
    const float* __restrict__ s0, const float* __restrict__ s1, const float* __restrict__ s2,
    const float* __restrict__ s3, const float* __restrict__ s4, const float* __restrict__ s5,
    short* __restrict__ wdst,
    const int* __restrict__ dst_dt, const int* __restrict__ dst_td,
    int* __restrict__ ghist, int* __restrict__ done,
    int* __restrict__ bbase, int* __restrict__ bcur,
    int nbt, int NB, int E) {
  __shared__ int lh[2048];
  __shared__ int sc[256];
  __shared__ int lastflag;
  int t = threadIdx.x;

  // --- weight bf16 conversion (6 x 128x128 matrices) ---
  if (blockIdx.x < 96) {
    int idx = blockIdx.x * 256 + t;
    int mat = idx >> 12;
    int pos = (idx & 4095) * 4;
    const float* s = (mat == 0) ? s0 : (mat == 1) ? s1 : (mat == 2) ? s2
                   : (mat == 3) ? s3 : (mat == 4) ? s4 : s5;
    float4 f = *(const float4*)(s + pos);
    short4 o;
    o.x = (short)f2bf(f.x); o.y = (short)f2bf(f.y);
    o.z = (short)f2bf(f.z); o.w = (short)f2bf(f.w);
    *(short4*)(wdst + mat * 16384 + pos) = o;
  }

  // --- coarse histogram with LDS pre-aggregation ---
#pragma unroll
  for (int k = 0; k < 8; ++k) lh[t + k * 256] = 0;
  __syncthreads();
  for (int i = blockIdx.x * 256 + t; i < E; i += gridDim.x * 256) {
    atomicAdd(&lh[dst_dt[i] >> 6], 1);
    atomicAdd(&lh[nbt + (dst_td[i] >> 6)], 1);
  }
  __syncthreads();
#pragma unroll
  for (int k = 0; k < 8; ++k) {
    int b = t + k * 256;
    int c = lh[b];
    if (b < NB && c) atomicAdd(&ghist[b], c);
  }
  __threadfence();
  __syncthreads();
  if (t == 0) {
    int prev = atomicAdd(done, 1);
    lastflag = (prev == (int)gridDim.x - 1);
  }
  __syncthreads();
  if (!lastflag) return;
  __threadfence();

  // --- bucket scan (single block, 8 buckets/thread) ---
  int i0 = t * 8;
  int c[8]; int s = 0;
#pragma unroll
  for (int k = 0; k < 8; ++k) {
    c[k] = (i0 + k < NB) ? atomicAdd(&ghist[i0 + k], 0) : 0;
    s += c[k];
  }
  sc[t] = s; __syncthreads();
  for (int st = 1; st < 256; st <<= 1) {
    int u = (t >= st) ? sc[t - st] : 0;
    __syncthreads(); sc[t] += u; __syncthreads();
  }
  int base = sc[t] - s;
#pragma unroll
  for (int k = 0; k < 8; ++k) {
    if (i0 + k < NB) { bbase[i0 + k] = base; bcur[i0 + k] = base; base += c[k]; }
  }
  if (t == 255) bbase[NB] = sc[255];
}

// Per-node MFMA precompute for BOTH node types in one launch.
// G channel of YG is pre-scaled by -log2e so gather's sigmoid uses exp2 directly.
__global__ __launch_bounds__(256) void node_mfma_all(
    const float* __restrict__ x_data, const float* __restrict__ x_task,
    const short* __restrict__ Wb,
    const float* __restrict__ bmn_dt, const float* __restrict__ bme_dt,
    const float* __restrict__ bgn_dt, const float* __restrict__ bge_dt,
    const float* __restrict__ bmn_td, const float* __restrict__ bme_td,
    const float* __restrict__ bgn_td, const float* __restrict__ bge_td,
    const float* __restrict__ bs_data, const float* __restrict__ bs_task,
    const float* __restrict__ bias_dt, const float* __restrict__ bias_td,
    unsigned int* __restrict__ YG_dt, unsigned int* __restrict__ YG_td,
    float* __restrict__ out, int n_data, int n_task, int gd) {
  __shared__ unsigned sh[32][132];
  const bool is_data = (int)blockIdx.x < gd;
  const float* x; const short *Wmnb, *Wgnb, *Wsb;
  const float *bmn, *bme, *bgn, *bge, *bs, *bias_other;
  unsigned* YG; float* out_init; int n, bid;
  if (is_data) {
    x = x_data; Wmnb = Wb; Wgnb = Wb + 16384; Wsb = Wb + 32768;
    bmn = bmn_dt; bme = bme_dt; bgn = bgn_dt; bge = bge_dt;
    bs = bs_data; bias_other = bias_td;
    YG = YG_dt; out_init = out; n = n_data; bid = blockIdx.x;
  } else {
    x = x_task; Wmnb = Wb + 3 * 16384; Wgnb = Wb + 4 * 16384; Wsb = Wb + 5 * 16384;
    bmn = bmn_td; bme = bme_td; bgn = bgn_td; bge = bge_td;
    bs = bs_task; bias_other = bias_dt;
    YG = YG_td; out_init = out + (size_t)n_data * D_DIM; n = n_task; bid = blockIdx.x - gd;
  }
  const int t = threadIdx.x;
  const int wave = t >> 6, lane = t & 63;
  const int q = lane >> 4, l15 = lane & 15;
  const int ng = wave >> 1;
  const int h = (wave & 1) * 64;
  const int base_node = bid * 32;
  const int node_base = base_node + ng * 16;

  short8 a[4];
  {
    int m = node_base + l15;
    int mc = m < n ? m : (n - 1);
    const float* xrow = x + (size_t)mc * D_DIM;
#pragma unroll
    for (int ks = 0; ks < 4; ++ks) {
      float4 f0 = *(const float4*)(xrow + ks * 32 + q * 8);
      float4 f1 = *(const float4*)(xrow + ks * 32 + q * 8 + 4);
      union { short8 s; __hip_bfloat162 hh[4]; } u;
      u.hh[0] = __float22bfloat162_rn({f0.x, f0.y});
      u.hh[1] = __float22bfloat162_rn({f0.z, f0.w});
      u.hh[2] = __float22bfloat162_rn({f1.x, f1.y});
      u.hh[3] = __float22bfloat162_rn({f1.z, f1.w});
      a[ks] = u.s;
    }
  }

  f32x4 accY[4], accG[4], accS[4];
#pragma unroll
  for (int nt = 0; nt < 4; ++nt) { accY[nt] = {0,0,0,0}; accG[nt] = {0,0,0,0}; accS[nt] = {0,0,0,0}; }

#pragma unroll
  for (int nt = 0; nt < 4; ++nt) {
    const int row = h + nt * 16 + l15;
#pragma unroll
    for (int ks = 0; ks < 4; ++ks) {
      const int off = row * D_DIM + ks * 32 + q * 8;
      short8 bm  = *(const short8*)(Wmnb + off);
      short8 bg  = *(const short8*)(Wgnb + off);
      short8 bsw = *(const short8*)(Wsb + off);
      accY[nt] = __builtin_amdgcn_mfma_f32_16x16x32_bf16(a[ks], bm,  accY[nt], 0, 0, 0);
      accG[nt] = __builtin_amdgcn_mfma_f32_16x16x32_bf16(a[ks], bg,  accG[nt], 0, 0, 0);
      accS[nt] = __builtin_amdgcn_mfma_f32_16x16x32_bf16(a[ks], bsw, accS[nt], 0, 0, 0);
    }
  }

#pragma unroll
  for (int nt = 0; nt < 4; ++nt) {
    int d = h + nt * 16 + l15;
    float bmv = bmn[d] + bme[d];
    float bgv = bgn[d] + bge[d];
#pragma unroll
    for (int r = 0; r < 4; ++r) {
      union { __hip_bfloat162 hh; unsigned u; } pck;
      pck.hh = __float22bfloat162_rn({accY[nt][r] + bmv,
                                      (accG[nt][r] + bgv) * NEG_LOG2E});
      sh[ng * 16 + q * 4 + r][d] = pck.u;
    }
  }
  __syncthreads();
#pragma unroll
  for (int it = 0; it < 4; ++it) {
    int idx = (it * 256 + t) * 4;
    int nl = idx >> 7, dd = idx & 127;
    int node = base_node + nl;
    if (node < n)
      *(uint4*)(YG + (size_t)node * D_DIM + dd) = *(const uint4*)&sh[nl][dd];
  }
  __syncthreads();

  float* shf = (float*)sh;
#pragma unroll
  for (int nt = 0; nt < 4; ++nt) {
    int d = h + nt * 16 + l15;
    float bsv = bs[d];
#pragma unroll
    for (int r = 0; r < 4; ++r)
      shf[(ng * 16 + q * 4 + r) * 132 + d] = sigmoid_fast(accS[nt][r] + bsv) + 0.5f;
  }
  __syncthreads();
#pragma unroll
  for (int it = 0; it < 4; ++it) {
    int idx = (it * 256 + t) * 4;
    int nl = idx >> 7, dd = idx & 127;
    int node = base_node + nl;
    if (node < n) {
      float4 xv = *(const float4*)(x + (size_t)node * D_DIM + dd);
      float4 bo = *(const float4*)(bias_other + dd);
      const float* sp = &shf[nl * 132 + dd];
      float4 o;
      o.x = sp[0] * xv.x + bo.x;
      o.y = sp[1] * xv.y + bo.y;
      o.z = sp[2] * xv.z + bo.z;
      o.w = sp[3] * xv.w + bo.w;
      *(float4*)(out_init + (size_t)node * D_DIM + dd) = o;
    }
  }
}

// Single partition pass: block handles 4096 edges of each list; per-bucket
// contiguous runs reserved with one global atomicAdd. Entry = {src, ef_hi24|loc6}.
__global__ __launch_bounds__(256) void sort_a_kernel(
    const int* __restrict__ src_dt, const int* __restrict__ dst_dt, const float* __restrict__ ef_dt,
    const int* __restrict__ src_td, const int* __restrict__ dst_td, const float* __restrict__ ef_td,
    int* __restrict__ bcur, int2* __restrict__ eA, int nbt, int NB, int E) {
  __shared__ int lh[2048];
  __shared__ int lcur[2048];
  int t = threadIdx.x;
#pragma unroll
  for (int k = 0; k < 8; ++k) lh[t + k * 256] = 0;
  __syncthreads();
  int e0 = blockIdx.x * 4096;
  int e1 = min(E, e0 + 4096);
  for (int i = e0 + t; i < e1; i += 256) {
    atomicAdd(&lh[dst_dt[i] >> 6], 1);
    atomicAdd(&lh[nbt + (dst_td[i] >> 6)], 1);
  }
  __syncthreads();
#pragma unroll
  for (int k = 0; k < 8; ++k) {
    int b = t + k * 256;
    int c = lh[b];
    if (b < NB && c) lcur[b] = atomicAdd(&bcur[b], c);
  }
  __syncthreads();
  for (int i = e0 + t; i < e1; i += 256) {
    int c = dst_dt[i];
    int pos = atomicAdd(&lcur[c >> 6], 1);
    eA[pos] = make_int2(src_dt[i],
        (int)((__float_as_uint(ef_dt[i]) & 0xFFFFFF00u) | (unsigned)(c & 63)));
    int cd = dst_td[i];
    int pos2 = atomicAdd(&lcur[nbt + (cd >> 6)], 1);
    eA[pos2] = make_int2(src_td[i],
        (int)((__float_as_uint(ef_td[i]) & 0xFFFFFF00u) | (unsigned)(cd & 63)));
  }
}

// Bucket gather: one block per 64-dst bucket. Output rows staged in LDS
// (init = self-layer result already in out). Accumulator is DE-INTERLEAVED:
// logical col c lives at phys (c>>1) + (c&1)*64, so the per-edge ds_add_f32
// pair hits banks lane%32 (2-way, free) instead of even banks (4-way).
// Main loop: named scalars, unconditional 8-batches -> registers, no scratch.
__global__ __launch_bounds__(256) void bucket_gather_kernel(
    const unsigned* __restrict__ YG_dt, const unsigned* __restrict__ YG_td,
    const int* __restrict__ bbase, const int2* __restrict__ eA,
    const float* __restrict__ Wme_dt, const float* __restrict__ Wge_dt,
    const float* __restrict__ Wme_td, const float* __restrict__ Wge_td,
    float* __restrict__ out, int nbt, int n_task, int n_data) {
  __shared__ float acc[64][D_DIM];          // 32 KB -> 5 blocks/CU
  const int b = blockIdx.x, t = threadIdx.x;
  const bool is_task = b < nbt;
  const unsigned* YG = is_task ? YG_dt : YG_td;
  const float* Wme = is_task ? Wme_dt : Wme_td;
  const float* Wge = is_task ? Wge_dt : Wge_td;
  int nloc; size_t orow0;
  if (is_task) { int c0 = b << 6; nloc = min(64, n_task - c0); orow0 = (size_t)(n_data + c0); }
  else         { int c0 = (b - nbt) << 6; nloc = min(64, n_data - c0); orow0 = (size_t)c0; }
  float* outp = out + orow0 * D_DIM;
  // stage init rows into de-interleaved LDS layout
  for (int i = t; i < (nloc << 5); i += 256) {
    int r = i >> 5, k = i & 31;              // quad k = logical cols 4k..4k+3
    float4 v = *(const float4*)(outp + r * D_DIM + (k << 2));
    *(float2*)&acc[r][2 * k]      = make_float2(v.x, v.z);
    *(float2*)&acc[r][64 + 2 * k] = make_float2(v.y, v.w);
  }
  const int base = bbase[b], end = bbase[b + 1];
  const int lane = t & 63, wave = t >> 6;
  float2 wme = *(const float2*)(Wme + 2 * lane);
  float2 wge = *(const float2*)(Wge + 2 * lane);
  float2 wge2 = {wge.x * NEG_LOG2E, wge.y * NEG_LOG2E};
  __syncthreads();

#define LD_E(i) int2 e##i = eA[p + i]
#define LD_Y(i) uint2 y##i = *(const uint2*)(YG + (size_t)e##i.x * D_DIM + 2 * lane)
#define PROC(i) do { \
    float f = __int_as_float(e##i.y & (int)0xFFFFFF00); \
    float g0 = __builtin_amdgcn_rcpf(1.0f + __builtin_amdgcn_exp2f(fmaf(f, wge2.x, bf_hi(y##i.x)))) - 0.5f; \
    float g1 = __builtin_amdgcn_rcpf(1.0f + __builtin_amdgcn_exp2f(fmaf(f, wge2.y, bf_hi(y##i.y)))) - 0.5f; \
    int loc = e##i.y & 63; \
    atomicAdd(&acc[loc][lane],      fmaf(f, wme.x, bf_lo(y##i.x)) * g0); \
    atomicAdd(&acc[loc][64 + lane], fmaf(f, wme.y, bf_lo(y##i.y)) * g1); \
  } while (0)

  int p = base + (wave << 3);
  for (; p + 8 <= end; p += 32) {
    LD_E(0); LD_E(1); LD_E(2); LD_E(3); LD_E(4); LD_E(5); LD_E(6); LD_E(7);
    LD_Y(0); LD_Y(1); LD_Y(2); LD_Y(3); LD_Y(4); LD_Y(5); LD_Y(6); LD_Y(7);
    PROC(0); PROC(1); PROC(2); PROC(3); PROC(4); PROC(5); PROC(6); PROC(7);
  }
  // tail: only the wave owning the final partial chunk enters; index is eA[p].
  for (; p < end; ++p) {
    int2 et = eA[p];
    uint2 yt = *(const uint2*)(YG + (size_t)et.x * D_DIM + 2 * lane);
    float f = __int_as_float(et.y & (int)0xFFFFFF00);
    float g0 = __builtin_amdgcn_rcpf(1.0f + __builtin_amdgcn_exp2f(fmaf(f, wge2.x, bf_hi(yt.x)))) - 0.5f;
    float g1 = __builtin_amdgcn_rcpf(1.0f + __builtin_amdgcn_exp2f(fmaf(f, wge2.y, bf_hi(yt.y)))) - 0.5f;
    int loc = et.y & 63;
    atomicAdd(&acc[loc][lane],      fmaf(f, wme.x, bf_lo(yt.x)) * g0);
    atomicAdd(&acc[loc][64 + lane], fmaf(f, wme.y, bf_lo(yt.y)) * g1);
  }
#undef LD_E
#undef LD_Y
#undef PROC

  __syncthreads();
  // ReLU + writeback (undo the de-interleave)
  for (int i = t; i < (nloc << 5); i += 256) {
    int r = i >> 5, k = i & 31;
    float2 lo = *(const float2*)&acc[r][2 * k];
    float2 hi = *(const float2*)&acc[r][64 + 2 * k];
    float4 v;
    v.x = fmaxf(lo.x, 0.0f); v.y = fmaxf(hi.x, 0.0f);
    v.z = fmaxf(lo.y, 0.0f); v.w = fmaxf(hi.y, 0.0f);
    *(float4*)(outp + r * D_DIM + (k << 2)) = v;
  }
}

extern "C" void kernel_launch(void* const* d_in, const int* in_sizes, int n_in,
                              void* d_out, int out_size, void* d_ws, size_t ws_size,
                              hipStream_t stream) {
  const float* x_data  = (const float*)d_in[0];
  const float* x_task  = (const float*)d_in[1];
  const int*   src_dt  = (const int*)d_in[2];
  const int*   dst_dt  = (const int*)d_in[3];
  const float* ef_dt   = (const float*)d_in[4];
  const int*   src_td  = (const int*)d_in[5];
  const int*   dst_td  = (const int*)d_in[6];
  const float* ef_td   = (const float*)d_in[7];
  const float* Wmn_dt  = (const float*)d_in[8];
  const float* bmn_dt  = (const float*)d_in[9];
  const float* Wme_dt  = (const float*)d_in[10];
  const float* bme_dt  = (const float*)d_in[11];
  const float* Wgn_dt  = (const float*)d_in[12];
  const float* bgn_dt  = (const float*)d_in[13];
  const float* Wge_dt  = (const float*)d_in[14];
  const float* bge_dt  = (const float*)d_in[15];
  const float* bias_dt = (const float*)d_in[16];
  const float* Wmn_td  = (const float*)d_in[17];
  const float* bmn_td  = (const float*)d_in[18];
  const float* Wme_td  = (const float*)d_in[19];
  const float* bme_td  = (const float*)d_in[20];
  const float* Wgn_td  = (const float*)d_in[21];
  const float* bgn_td  = (const float*)d_in[22];
  const float* Wge_td  = (const float*)d_in[23];
  const float* bge_td  = (const float*)d_in[24];
  const float* bias_td = (const float*)d_in[25];
  const float* Ws_data = (const float*)d_in[26];
  const float* bs_data = (const float*)d_in[27];
  const float* Ws_task = (const float*)d_in[28];
  const float* bs_task = (const float*)d_in[29];
  float* out = (float*)d_out;

  const int N_DATA = in_sizes[0] / D_DIM;   // 100000
  const int N_TASK = in_sizes[1] / D_DIM;   // 20000
  const int E = in_sizes[2];                // 1000000
  const int NBT = (N_TASK + 63) >> 6;       // 313 task buckets (64 dsts each)
  const int NBD = (N_DATA + 63) >> 6;       // 1563 data buckets (64 dsts each)
  const int NB = NBT + NBD;                 // 1876 (<= 2048)
  const int GD = (N_DATA + 31) / 32;
  const int GT = (N_TASK + 31) / 32;

  char* ws = (char*)d_ws;
  size_t off = 0;
  auto alloc = [&](size_t bytes) { void* p = ws + off; off += (bytes + 255) & ~(size_t)255; return p; };
  unsigned int* YG_dt = (unsigned int*)alloc((size_t)N_DATA * D_DIM * 4);
  unsigned int* YG_td = (unsigned int*)alloc((size_t)N_TASK * D_DIM * 4);
  int2* eA     = (int2*)alloc((size_t)2 * E * 8);
  int*  ghist  = (int*)alloc(2560 * 4);     // 2048 hist + done counter @2048
  int*  bbase  = (int*)alloc(2304 * 4);
  int*  bcur   = (int*)alloc(2304 * 4);
  short* Wb    = (short*)alloc((size_t)6 * 16384 * 2);
  (void)ws_size; (void)n_in; (void)out_size;

  hipMemsetAsync(ghist, 0, 2560 * 4, stream);

  fused_pre_kernel<<<256, 256, 0, stream>>>(
      Wmn_dt, Wgn_dt, Ws_data, Wmn_td, Wgn_td, Ws_task, Wb,
      dst_dt, dst_td, ghist, ghist + 2048, bbase, bcur,
      NBT, NB, E);

  node_mfma_all<<<GD + GT, 256, 0, stream>>>(
      x_data, x_task, Wb,
      bmn_dt, bme_dt, bgn_dt, bge_dt,
      bmn_td, bme_td, bgn_td, bge_td,
      bs_data, bs_task, bias_dt, bias_td,
      YG_dt, YG_td, out, N_DATA, N_TASK, GD);

  sort_a_kernel<<<(E + 4095) / 4096, 256, 0, stream>>>(
      src_dt, dst_dt, ef_dt, src_td, dst_td, ef_td, bcur, eA, NBT, NB, E);

  bucket_gather_kernel<<<NB, 256, 0, stream>>>(
      YG_dt, YG_td, bbase, eA, Wme_dt, Wge_dt, Wme_td, Wge_td,
      out, NBT, N_TASK, N_DATA);
}

// Round 6
// 621.288 us; speedup vs baseline: 2.8124x; 2.7993x over previous
//
#include <hip/hip_runtime.h>
#include <hip/hip_bf16.h>
#include <cstdint>
#include <cstddef>

#define D_DIM 128
#define NEG_LOG2E (-1.44269504f)

typedef __attribute__((ext_vector_type(8))) short short8;
typedef __attribute__((ext_vector_type(4))) float f32x4;

__device__ __forceinline__ float sigmoid_fast(float z) {
  return __builtin_amdgcn_rcpf(1.0f + __expf(-z));
}

__device__ __forceinline__ unsigned short f2bf(float f) {
  union { float f; unsigned u; } v; v.f = f;
  unsigned r = v.u + 0x7FFF + ((v.u >> 16) & 1);   // RNE
  return (unsigned short)(r >> 16);
}
__device__ __forceinline__ float bf_lo(unsigned u) { return __uint_as_float(u << 16); }
__device__ __forceinline__ float bf_hi(unsigned u) { return __uint_as_float(u & 0xFFFF0000u); }

// k1: wconv (blocks 0..95) + per-dst histogram (all blocks, vectorized int4,
// global atomics into 120k-bin cnt[]).
__global__ __launch_bounds__(256) void wconv_hist_kernel(
    const float* __restrict__ s0, const float* __restrict__ s1, const float* __restrict__ s2,
    const float* __restrict__ s3, const float* __restrict__ s4, const float* __restrict__ s5,
    short* __restrict__ wdst,
    const int* __restrict__ dst_dt, const int* __restrict__ dst_td,
    int* __restrict__ cnt, int n_task, int E) {
  int t = threadIdx.x;
  if (blockIdx.x < 96) {
    int idx = blockIdx.x * 256 + t;
    int mat = idx >> 12;
    int pos = (idx & 4095) * 4;
    const float* s = (mat == 0) ? s0 : (mat == 1) ? s1 : (mat == 2) ? s2
                   : (mat == 3) ? s3 : (mat == 4) ? s4 : s5;
    float4 f = *(const float4*)(s + pos);
    short4 o;
    o.x = (short)f2bf(f.x); o.y = (short)f2bf(f.y);
    o.z = (short)f2bf(f.z); o.w = (short)f2bf(f.w);
    *(short4*)(wdst + mat * 16384 + pos) = o;
  }
  int E4 = E >> 2;
  int i = blockIdx.x * 256 + t;
  if (i < E4) {
    int4 a = *(const int4*)(dst_dt + 4 * i);
    atomicAdd(&cnt[a.x], 1); atomicAdd(&cnt[a.y], 1);
    atomicAdd(&cnt[a.z], 1); atomicAdd(&cnt[a.w], 1);
    int4 b = *(const int4*)(dst_td + 4 * i);
    atomicAdd(&cnt[n_task + b.x], 1); atomicAdd(&cnt[n_task + b.y], 1);
    atomicAdd(&cnt[n_task + b.z], 1); atomicAdd(&cnt[n_task + b.w], 1);
  }
  if (blockIdx.x == 0 && t < (E & 3)) {
    int j = (E & ~3) + t;
    atomicAdd(&cnt[dst_dt[j]], 1);
    atomicAdd(&cnt[n_task + dst_td[j]], 1);
  }
}

// k2: per-256-bin block sums.
__global__ __launch_bounds__(256) void scan_p1_kernel(
    const int* __restrict__ cnt, int* __restrict__ bsum, int n_tot) {
  __shared__ int red[256];
  int t = threadIdx.x;
  int idx = blockIdx.x * 256 + t;
  red[t] = (idx < n_tot) ? cnt[idx] : 0;
  __syncthreads();
  for (int s = 128; s > 0; s >>= 1) {
    if (t < s) red[t] += red[t + s];
    __syncthreads();
  }
  if (t == 0) bsum[blockIdx.x] = red[0];
}

// k3: scan of block sums (<=512 blocks); writes total sentinel.
__global__ __launch_bounds__(512) void scan_p2_kernel(
    const int* __restrict__ bsum, int* __restrict__ bpre,
    int* __restrict__ offs, int SB, int n_tot) {
  __shared__ int sc[512];
  int t = threadIdx.x;
  int v = (t < SB) ? bsum[t] : 0;
  sc[t] = v; __syncthreads();
  for (int s = 1; s < 512; s <<= 1) {
    int u = (t >= s) ? sc[t - s] : 0;
    __syncthreads(); sc[t] += u; __syncthreads();
  }
  if (t < SB) bpre[t] = sc[t] - v;
  if (t == 511) offs[n_tot] = sc[511];
}

// k4: final per-dst exclusive offsets + cursors.
__global__ __launch_bounds__(256) void scan_p3_kernel(
    const int* __restrict__ cnt, const int* __restrict__ bpre,
    int* __restrict__ offs, int* __restrict__ cur, int n_tot) {
  __shared__ int sc[256];
  int t = threadIdx.x;
  int idx = blockIdx.x * 256 + t;
  int v = (idx < n_tot) ? cnt[idx] : 0;
  sc[t] = v; __syncthreads();
  for (int s = 1; s < 256; s <<= 1) {
    int u = (t >= s) ? sc[t - s] : 0;
    __syncthreads(); sc[t] += u; __syncthreads();
  }
  if (idx < n_tot) {
    int base = bpre[blockIdx.x] + sc[t] - v;
    offs[idx] = base;
    cur[idx] = base;
  }
}

// Per-node MFMA precompute for BOTH node types in one launch.
// G channel of YG is pre-scaled by -log2e so gather's sigmoid uses exp2 directly.
__global__ __launch_bounds__(256) void node_mfma_all(
    const float* __restrict__ x_data, const float* __restrict__ x_task,
    const short* __restrict__ Wb,
    const float* __restrict__ bmn_dt, const float* __restrict__ bme_dt,
    const float* __restrict__ bgn_dt, const float* __restrict__ bge_dt,
    const float* __restrict__ bmn_td, const float* __restrict__ bme_td,
    const float* __restrict__ bgn_td, const float* __restrict__ bge_td,
    const float* __restrict__ bs_data, const float* __restrict__ bs_task,
    const float* __restrict__ bias_dt, const float* __restrict__ bias_td,
    unsigned int* __restrict__ YG_dt, unsigned int* __restrict__ YG_td,
    float* __restrict__ out, int n_data, int n_task, int gd) {
  __shared__ unsigned sh[32][132];
  const bool is_data = (int)blockIdx.x < gd;
  const float* x; const short *Wmnb, *Wgnb, *Wsb;
  const float *bmn, *bme, *bgn, *bge, *bs, *bias_other;
  unsigned* YG; float* out_init; int n, bid;
  if (is_data) {
    x = x_data; Wmnb = Wb; Wgnb = Wb + 16384; Wsb = Wb + 32768;
    bmn = bmn_dt; bme = bme_dt; bgn = bgn_dt; bge = bge_dt;
    bs = bs_data; bias_other = bias_td;
    YG = YG_dt; out_init = out; n = n_data; bid = blockIdx.x;
  } else {
    x = x_task; Wmnb = Wb + 3 * 16384; Wgnb = Wb + 4 * 16384; Wsb = Wb + 5 * 16384;
    bmn = bmn_td; bme = bme_td; bgn = bgn_td; bge = bge_td;
    bs = bs_task; bias_other = bias_dt;
    YG = YG_td; out_init = out + (size_t)n_data * D_DIM; n = n_task; bid = blockIdx.x - gd;
  }
  const int t = threadIdx.x;
  const int wave = t >> 6, lane = t & 63;
  const int q = lane >> 4, l15 = lane & 15;
  const int ng = wave >> 1;
  const int h = (wave & 1) * 64;
  const int base_node = bid * 32;
  const int node_base = base_node + ng * 16;

  short8 a[4];
  {
    int m = node_base + l15;
    int mc = m < n ? m : (n - 1);
    const float* xrow = x + (size_t)mc * D_DIM;
#pragma unroll
    for (int ks = 0; ks < 4; ++ks) {
      float4 f0 = *(const float4*)(xrow + ks * 32 + q * 8);
      float4 f1 = *(const float4*)(xrow + ks * 32 + q * 8 + 4);
      union { short8 s; __hip_bfloat162 hh[4]; } u;
      u.hh[0] = __float22bfloat162_rn({f0.x, f0.y});
      u.hh[1] = __float22bfloat162_rn({f0.z, f0.w});
      u.hh[2] = __float22bfloat162_rn({f1.x, f1.y});
      u.hh[3] = __float22bfloat162_rn({f1.z, f1.w});
      a[ks] = u.s;
    }
  }

  f32x4 accY[4], accG[4], accS[4];
#pragma unroll
  for (int nt = 0; nt < 4; ++nt) { accY[nt] = {0,0,0,0}; accG[nt] = {0,0,0,0}; accS[nt] = {0,0,0,0}; }

#pragma unroll
  for (int nt = 0; nt < 4; ++nt) {
    const int row = h + nt * 16 + l15;
#pragma unroll
    for (int ks = 0; ks < 4; ++ks) {
      const int off = row * D_DIM + ks * 32 + q * 8;
      short8 bm  = *(const short8*)(Wmnb + off);
      short8 bg  = *(const short8*)(Wgnb + off);
      short8 bsw = *(const short8*)(Wsb + off);
      accY[nt] = __builtin_amdgcn_mfma_f32_16x16x32_bf16(a[ks], bm,  accY[nt], 0, 0, 0);
      accG[nt] = __builtin_amdgcn_mfma_f32_16x16x32_bf16(a[ks], bg,  accG[nt], 0, 0, 0);
      accS[nt] = __builtin_amdgcn_mfma_f32_16x16x32_bf16(a[ks], bsw, accS[nt], 0, 0, 0);
    }
  }

#pragma unroll
  for (int nt = 0; nt < 4; ++nt) {
    int d = h + nt * 16 + l15;
    float bmv = bmn[d] + bme[d];
    float bgv = bgn[d] + bge[d];
#pragma unroll
    for (int r = 0; r < 4; ++r) {
      union { __hip_bfloat162 hh; unsigned u; } pck;
      pck.hh = __float22bfloat162_rn({accY[nt][r] + bmv,
                                      (accG[nt][r] + bgv) * NEG_LOG2E});
      sh[ng * 16 + q * 4 + r][d] = pck.u;
    }
  }
  __syncthreads();
#pragma unroll
  for (int it = 0; it < 4; ++it) {
    int idx = (it * 256 + t) * 4;
    int nl = idx >> 7, dd = idx & 127;
    int node = base_node + nl;
    if (node < n)
      *(uint4*)(YG + (size_t)node * D_DIM + dd) = *(const uint4*)&sh[nl][dd];
  }
  __syncthreads();

  float* shf = (float*)sh;
#pragma unroll
  for (int nt = 0; nt < 4; ++nt) {
    int d = h + nt * 16 + l15;
    float bsv = bs[d];
#pragma unroll
    for (int r = 0; r < 4; ++r)
      shf[(ng * 16 + q * 4 + r) * 132 + d] = sigmoid_fast(accS[nt][r] + bsv) + 0.5f;
  }
  __syncthreads();
#pragma unroll
  for (int it = 0; it < 4; ++it) {
    int idx = (it * 256 + t) * 4;
    int nl = idx >> 7, dd = idx & 127;
    int node = base_node + nl;
    if (node < n) {
      float4 xv = *(const float4*)(x + (size_t)node * D_DIM + dd);
      float4 bo = *(const float4*)(bias_other + dd);
      const float* sp = &shf[nl * 132 + dd];
      float4 o;
      o.x = sp[0] * xv.x + bo.x;
      o.y = sp[1] * xv.y + bo.y;
      o.z = sp[2] * xv.z + bo.z;
      o.w = sp[3] * xv.w + bo.w;
      *(float4*)(out_init + (size_t)node * D_DIM + dd) = o;
    }
  }
}

// k6: direct scatter to final per-dst positions. Entry = {src, ef (full f32)}.
__global__ __launch_bounds__(256) void scatter_kernel(
    const int* __restrict__ src_dt, const int* __restrict__ dst_dt, const float* __restrict__ ef_dt,
    const int* __restrict__ src_td, const int* __restrict__ dst_td, const float* __restrict__ ef_td,
    int* __restrict__ cur, int2* __restrict__ eB, int n_task, int E) {
  int i = blockIdx.x * 256 + threadIdx.x;
  int E4 = E >> 2;
  if (i < E4) {
    int4 s = *(const int4*)(src_dt + 4 * i);
    int4 d = *(const int4*)(dst_dt + 4 * i);
    float4 f = *(const float4*)(ef_dt + 4 * i);
    int p0 = atomicAdd(&cur[d.x], 1); eB[p0] = make_int2(s.x, __float_as_int(f.x));
    int p1 = atomicAdd(&cur[d.y], 1); eB[p1] = make_int2(s.y, __float_as_int(f.y));
    int p2 = atomicAdd(&cur[d.z], 1); eB[p2] = make_int2(s.z, __float_as_int(f.z));
    int p3 = atomicAdd(&cur[d.w], 1); eB[p3] = make_int2(s.w, __float_as_int(f.w));
    s = *(const int4*)(src_td + 4 * i);
    d = *(const int4*)(dst_td + 4 * i);
    f = *(const float4*)(ef_td + 4 * i);
    int q0 = atomicAdd(&cur[n_task + d.x], 1); eB[q0] = make_int2(s.x, __float_as_int(f.x));
    int q1 = atomicAdd(&cur[n_task + d.y], 1); eB[q1] = make_int2(s.y, __float_as_int(f.y));
    int q2 = atomicAdd(&cur[n_task + d.z], 1); eB[q2] = make_int2(s.z, __float_as_int(f.z));
    int q3 = atomicAdd(&cur[n_task + d.w], 1); eB[q3] = make_int2(s.w, __float_as_int(f.w));
  }
  if (blockIdx.x == 0 && threadIdx.x < (E & 3)) {
    int j = (E & ~3) + threadIdx.x;
    int p = atomicAdd(&cur[dst_dt[j]], 1);
    eB[p] = make_int2(src_dt[j], __float_as_int(ef_dt[j]));
    int q = atomicAdd(&cur[n_task + dst_td[j]], 1);
    eB[q] = make_int2(src_td[j], __float_as_int(ef_td[j]));
  }
}

// k7: combined gather. Wave w<n_task -> task dst (dt conv), else data dst.
// G channel of YG is pre-scaled by -log2e; wge2 = -log2e * wge.
__device__ __forceinline__ void gstep(float2& acc, int2 e, const unsigned* __restrict__ YG,
                                      int lane, float2 wme, float2 wge2) {
  uint2 yg = *(const uint2*)(YG + (size_t)e.x * D_DIM + 2 * lane);
  float f = __int_as_float(e.y);
  float g0 = __builtin_amdgcn_rcpf(1.0f + __builtin_amdgcn_exp2f(fmaf(f, wge2.x, bf_hi(yg.x)))) - 0.5f;
  float g1 = __builtin_amdgcn_rcpf(1.0f + __builtin_amdgcn_exp2f(fmaf(f, wge2.y, bf_hi(yg.y)))) - 0.5f;
  acc.x = fmaf(fmaf(f, wme.x, bf_lo(yg.x)), g0, acc.x);
  acc.y = fmaf(fmaf(f, wme.y, bf_lo(yg.y)), g1, acc.y);
}

__global__ __launch_bounds__(256) void gather_kernel(
    const unsigned* __restrict__ YG_dt, const unsigned* __restrict__ YG_td,
    const int* __restrict__ offsets, const int2* __restrict__ edata,
    const float* __restrict__ Wme_dt, const float* __restrict__ Wge_dt,
    const float* __restrict__ Wme_td, const float* __restrict__ Wge_td,
    float* __restrict__ out, int n_task, int n_data) {
  int w = (int)((blockIdx.x * 256u + threadIdx.x) >> 6);
  int lane = threadIdx.x & 63;
  if (w >= n_task + n_data) return;
  bool is_dt = w < n_task;
  const unsigned* YG = is_dt ? YG_dt : YG_td;
  const float* Wme = is_dt ? Wme_dt : Wme_td;
  const float* Wge = is_dt ? Wge_dt : Wge_td;
  size_t orow = is_dt ? (size_t)(n_data + w) : (size_t)(w - n_task);
  int beg = __builtin_amdgcn_readfirstlane(offsets[w]);
  int end = __builtin_amdgcn_readfirstlane(offsets[w + 1]);
  float2 wme = *(const float2*)(Wme + 2 * lane);
  float2 wge = *(const float2*)(Wge + 2 * lane);
  float2 wge2 = {wge.x * NEG_LOG2E, wge.y * NEG_LOG2E};
  float* op = out + orow * D_DIM + 2 * lane;
  float2 acc0 = *(const float2*)op;
  float2 acc1 = {0.0f, 0.0f};
  int p = beg;
  for (; p + 8 <= end; p += 8) {
    int2 e0 = edata[p],     e1 = edata[p + 1], e2 = edata[p + 2], e3 = edata[p + 3];
    int2 e4 = edata[p + 4], e5 = edata[p + 5], e6 = edata[p + 6], e7 = edata[p + 7];
    gstep(acc0, e0, YG, lane, wme, wge2);
    gstep(acc1, e1, YG, lane, wme, wge2);
    gstep(acc0, e2, YG, lane, wme, wge2);
    gstep(acc1, e3, YG, lane, wme, wge2);
    gstep(acc0, e4, YG, lane, wme, wge2);
    gstep(acc1, e5, YG, lane, wme, wge2);
    gstep(acc0, e6, YG, lane, wme, wge2);
    gstep(acc1, e7, YG, lane, wme, wge2);
  }
  for (; p + 2 <= end; p += 2) {
    int2 e0 = edata[p], e1 = edata[p + 1];
    gstep(acc0, e0, YG, lane, wme, wge2);
    gstep(acc1, e1, YG, lane, wme, wge2);
  }
  if (p < end) gstep(acc0, edata[p], YG, lane, wme, wge2);
  acc0.x = fmaxf(acc0.x + acc1.x, 0.0f);
  acc0.y = fmaxf(acc0.y + acc1.y, 0.0f);
  *(float2*)op = acc0;
}

extern "C" void kernel_launch(void* const* d_in, const int* in_sizes, int n_in,
                              void* d_out, int out_size, void* d_ws, size_t ws_size,
                              hipStream_t stream) {
  const float* x_data  = (const float*)d_in[0];
  const float* x_task  = (const float*)d_in[1];
  const int*   src_dt  = (const int*)d_in[2];
  const int*   dst_dt  = (const int*)d_in[3];
  const float* ef_dt   = (const float*)d_in[4];
  const int*   src_td  = (const int*)d_in[5];
  const int*   dst_td  = (const int*)d_in[6];
  const float* ef_td   = (const float*)d_in[7];
  const float* Wmn_dt  = (const float*)d_in[8];
  const float* bmn_dt  = (const float*)d_in[9];
  const float* Wme_dt  = (const float*)d_in[10];
  const float* bme_dt  = (const float*)d_in[11];
  const float* Wgn_dt  = (const float*)d_in[12];
  const float* bgn_dt  = (const float*)d_in[13];
  const float* Wge_dt  = (const float*)d_in[14];
  const float* bge_dt  = (const float*)d_in[15];
  const float* bias_dt = (const float*)d_in[16];
  const float* Wmn_td  = (const float*)d_in[17];
  const float* bmn_td  = (const float*)d_in[18];
  const float* Wme_td  = (const float*)d_in[19];
  const float* bme_td  = (const float*)d_in[20];
  const float* Wgn_td  = (const float*)d_in[21];
  const float* bgn_td  = (const float*)d_in[22];
  const float* Wge_td  = (const float*)d_in[23];
  const float* bge_td  = (const float*)d_in[24];
  const float* bias_td = (const float*)d_in[25];
  const float* Ws_data = (const float*)d_in[26];
  const float* bs_data = (const float*)d_in[27];
  const float* Ws_task = (const float*)d_in[28];
  const float* bs_task = (const float*)d_in[29];
  float* out = (float*)d_out;

  const int N_DATA = in_sizes[0] / D_DIM;   // 100000
  const int N_TASK = in_sizes[1] / D_DIM;   // 20000
  const int E = in_sizes[2];                // 1000000
  const int N_TOT = N_TASK + N_DATA;        // 120000
  const int SB = (N_TOT + 255) / 256;       // 469 (<=512)
  const int GD = (N_DATA + 31) / 32;
  const int GT = (N_TASK + 31) / 32;

  char* ws = (char*)d_ws;
  size_t off = 0;
  auto alloc = [&](size_t bytes) { void* p = ws + off; off += (bytes + 255) & ~(size_t)255; return p; };
  unsigned int* YG_dt = (unsigned int*)alloc((size_t)N_DATA * D_DIM * 4);
  unsigned int* YG_td = (unsigned int*)alloc((size_t)N_TASK * D_DIM * 4);
  int2* eB    = (int2*)alloc((size_t)2 * E * 8);
  int*  offs  = (int*)alloc((size_t)(N_TOT + 1) * 4);
  int*  cur   = (int*)alloc((size_t)N_TOT * 4);
  int*  cnt   = (int*)alloc((size_t)N_TOT * 4);
  int*  bsum  = (int*)alloc(512 * 4);
  int*  bpre  = (int*)alloc(512 * 4);
  short* Wb   = (short*)alloc((size_t)6 * 16384 * 2);
  (void)ws_size; (void)n_in; (void)out_size;

  hipMemsetAsync(cnt, 0, (size_t)N_TOT * 4, stream);

  wconv_hist_kernel<<<1024, 256, 0, stream>>>(
      Wmn_dt, Wgn_dt, Ws_data, Wmn_td, Wgn_td, Ws_task, Wb,
      dst_dt, dst_td, cnt, N_TASK, E);

  scan_p1_kernel<<<SB, 256, 0, stream>>>(cnt, bsum, N_TOT);
  scan_p2_kernel<<<1, 512, 0, stream>>>(bsum, bpre, offs, SB, N_TOT);
  scan_p3_kernel<<<SB, 256, 0, stream>>>(cnt, bpre, offs, cur, N_TOT);

  node_mfma_all<<<GD + GT, 256, 0, stream>>>(
      x_data, x_task, Wb,
      bmn_dt, bme_dt, bgn_dt, bge_dt,
      bmn_td, bme_td, bgn_td, bge_td,
      bs_data, bs_task, bias_dt, bias_td,
      YG_dt, YG_td, out, N_DATA, N_TASK, GD);

  scatter_kernel<<<1024, 256, 0, stream>>>(
      src_dt, dst_dt, ef_dt, src_td, dst_td, ef_td, cur, eB, N_TASK, E);

  gather_kernel<<<(N_TOT + 3) / 4, 256, 0, stream>>>(
      YG_dt, YG_td, offs, eB, Wme_dt, Wge_dt, Wme_td, Wge_td, out, N_TASK, N_DATA);
}

// Round 8
// 477.119 us; speedup vs baseline: 3.6623x; 1.3022x over previous
//
#include <hip/hip_runtime.h>
#include <hip/hip_bf16.h>
#include <cstdint>
#include <cstddef>

#define D_DIM 128
#define NEG_LOG2E (-1.44269504f)

typedef __attribute__((ext_vector_type(8))) short short8;
typedef __attribute__((ext_vector_type(4))) float f32x4;

__device__ __forceinline__ float sigmoid_fast(float z) {
  return __builtin_amdgcn_rcpf(1.0f + __expf(-z));
}

__device__ __forceinline__ unsigned short f2bf(float f) {
  union { float f; unsigned u; } v; v.f = f;
  unsigned r = v.u + 0x7FFF + ((v.u >> 16) & 1);   // RNE
  return (unsigned short)(r >> 16);
}
__device__ __forceinline__ float bf_lo(unsigned u) { return __uint_as_float(u << 16); }
__device__ __forceinline__ float bf_hi(unsigned u) { return __uint_as_float(u & 0xFFFF0000u); }

// Fused: wconv (blocks 0..95) + coarse histogram (all blocks, int4-vectorized)
// + bucket scan (by the last block to finish, device-scope done-counter).
// Buckets: task 64 dsts (nbt), data 256 dsts.
__global__ __launch_bounds__(256) void fused_pre_kernel(
    const float* __restrict__ s0, const float* __restrict__ s1, const float* __restrict__ s2,
    const float* __restrict__ s3, const float* __restrict__ s4, const float* __restrict__ s5,
    short* __restrict__ wdst,
    const int* __restrict__ dst_dt, const int* __restrict__ dst_td,
    int* __restrict__ ghist, int* __restrict__ done,
    int* __restrict__ bbase, int* __restrict__ bcur, int* __restrict__ offsets,
    int nbt, int NB, int E, int n_tot) {
  __shared__ int lh[768];
  __shared__ int sc[256];
  __shared__ int lastflag;
  int t = threadIdx.x;

  // --- weight bf16 conversion (6 x 128x128 matrices) ---
  if (blockIdx.x < 96) {
    int idx = blockIdx.x * 256 + t;
    int mat = idx >> 12;
    int pos = (idx & 4095) * 4;
    const float* s = (mat == 0) ? s0 : (mat == 1) ? s1 : (mat == 2) ? s2
                   : (mat == 3) ? s3 : (mat == 4) ? s4 : s5;
    float4 f = *(const float4*)(s + pos);
    short4 o;
    o.x = (short)f2bf(f.x); o.y = (short)f2bf(f.y);
    o.z = (short)f2bf(f.z); o.w = (short)f2bf(f.w);
    *(short4*)(wdst + mat * 16384 + pos) = o;
  }

  // --- coarse histogram with LDS pre-aggregation (int4 loads) ---
  lh[t] = 0; lh[t + 256] = 0; lh[t + 512] = 0;
  __syncthreads();
  int E4 = E >> 2;
  for (int i = blockIdx.x * 256 + t; i < E4; i += gridDim.x * 256) {
    int4 a = *(const int4*)(dst_dt + 4 * i);
    atomicAdd(&lh[a.x >> 6], 1); atomicAdd(&lh[a.y >> 6], 1);
    atomicAdd(&lh[a.z >> 6], 1); atomicAdd(&lh[a.w >> 6], 1);
    int4 b = *(const int4*)(dst_td + 4 * i);
    atomicAdd(&lh[nbt + (b.x >> 8)], 1); atomicAdd(&lh[nbt + (b.y >> 8)], 1);
    atomicAdd(&lh[nbt + (b.z >> 8)], 1); atomicAdd(&lh[nbt + (b.w >> 8)], 1);
  }
  if (blockIdx.x == 0 && t < (E & 3)) {
    int j = (E & ~3) + t;
    atomicAdd(&lh[dst_dt[j] >> 6], 1);
    atomicAdd(&lh[nbt + (dst_td[j] >> 8)], 1);
  }
  __syncthreads();
#pragma unroll
  for (int k = 0; k < 3; ++k) {
    int b = t + k * 256;
    int c = lh[b];
    if (b < NB && c) atomicAdd(&ghist[b], c);
  }
  __threadfence();
  __syncthreads();
  if (t == 0) {
    int prev = atomicAdd(done, 1);
    lastflag = (prev == (int)gridDim.x - 1);
  }
  __syncthreads();
  if (!lastflag) return;
  __threadfence();

  // --- bucket scan (single block) ---
  int i0 = t * 3;
  int c0 = (i0     < NB) ? atomicAdd(&ghist[i0],     0) : 0;
  int c1 = (i0 + 1 < NB) ? atomicAdd(&ghist[i0 + 1], 0) : 0;
  int c2 = (i0 + 2 < NB) ? atomicAdd(&ghist[i0 + 2], 0) : 0;
  int tot = c0 + c1 + c2;
  sc[t] = tot; __syncthreads();
  for (int s = 1; s < 256; s <<= 1) {
    int u = (t >= s) ? sc[t - s] : 0;
    __syncthreads(); sc[t] += u; __syncthreads();
  }
  int base = sc[t] - tot;
  if (i0     < NB) { bbase[i0]     = base;           bcur[i0]     = base; }
  if (i0 + 1 < NB) { bbase[i0 + 1] = base + c0;      bcur[i0 + 1] = base + c0; }
  if (i0 + 2 < NB) { bbase[i0 + 2] = base + c0 + c1; bcur[i0 + 2] = base + c0 + c1; }
  if (t == 255) { bbase[NB] = sc[255]; offsets[n_tot] = sc[255]; }
}

// Per-node MFMA precompute for BOTH node types in one launch.
// G channel of YG is pre-scaled by -log2e so gather's sigmoid uses exp2 directly.
__global__ __launch_bounds__(256) void node_mfma_all(
    const float* __restrict__ x_data, const float* __restrict__ x_task,
    const short* __restrict__ Wb,
    const float* __restrict__ bmn_dt, const float* __restrict__ bme_dt,
    const float* __restrict__ bgn_dt, const float* __restrict__ bge_dt,
    const float* __restrict__ bmn_td, const float* __restrict__ bme_td,
    const float* __restrict__ bgn_td, const float* __restrict__ bge_td,
    const float* __restrict__ bs_data, const float* __restrict__ bs_task,
    const float* __restrict__ bias_dt, const float* __restrict__ bias_td,
    unsigned int* __restrict__ YG_dt, unsigned int* __restrict__ YG_td,
    float* __restrict__ out, int n_data, int n_task, int gd) {
  __shared__ unsigned sh[32][132];
  const bool is_data = (int)blockIdx.x < gd;
  const float* x; const short *Wmnb, *Wgnb, *Wsb;
  const float *bmn, *bme, *bgn, *bge, *bs, *bias_other;
  unsigned* YG; float* out_init; int n, bid;
  if (is_data) {
    x = x_data; Wmnb = Wb; Wgnb = Wb + 16384; Wsb = Wb + 32768;
    bmn = bmn_dt; bme = bme_dt; bgn = bgn_dt; bge = bge_dt;
    bs = bs_data; bias_other = bias_td;
    YG = YG_dt; out_init = out; n = n_data; bid = blockIdx.x;
  } else {
    x = x_task; Wmnb = Wb + 3 * 16384; Wgnb = Wb + 4 * 16384; Wsb = Wb + 5 * 16384;
    bmn = bmn_td; bme = bme_td; bgn = bgn_td; bge = bge_td;
    bs = bs_task; bias_other = bias_dt;
    YG = YG_td; out_init = out + (size_t)n_data * D_DIM; n = n_task; bid = blockIdx.x - gd;
  }
  const int t = threadIdx.x;
  const int wave = t >> 6, lane = t & 63;
  const int q = lane >> 4, l15 = lane & 15;
  const int ng = wave >> 1;
  const int h = (wave & 1) * 64;
  const int base_node = bid * 32;
  const int node_base = base_node + ng * 16;

  short8 a[4];
  {
    int m = node_base + l15;
    int mc = m < n ? m : (n - 1);
    const float* xrow = x + (size_t)mc * D_DIM;
#pragma unroll
    for (int ks = 0; ks < 4; ++ks) {
      float4 f0 = *(const float4*)(xrow + ks * 32 + q * 8);
      float4 f1 = *(const float4*)(xrow + ks * 32 + q * 8 + 4);
      union { short8 s; __hip_bfloat162 hh[4]; } u;
      u.hh[0] = __float22bfloat162_rn({f0.x, f0.y});
      u.hh[1] = __float22bfloat162_rn({f0.z, f0.w});
      u.hh[2] = __float22bfloat162_rn({f1.x, f1.y});
      u.hh[3] = __float22bfloat162_rn({f1.z, f1.w});
      a[ks] = u.s;
    }
  }

  f32x4 accY[4], accG[4], accS[4];
#pragma unroll
  for (int nt = 0; nt < 4; ++nt) { accY[nt] = {0,0,0,0}; accG[nt] = {0,0,0,0}; accS[nt] = {0,0,0,0}; }

#pragma unroll
  for (int nt = 0; nt < 4; ++nt) {
    const int row = h + nt * 16 + l15;
#pragma unroll
    for (int ks = 0; ks < 4; ++ks) {
      const int off = row * D_DIM + ks * 32 + q * 8;
      short8 bm  = *(const short8*)(Wmnb + off);
      short8 bg  = *(const short8*)(Wgnb + off);
      short8 bsw = *(const short8*)(Wsb + off);
      accY[nt] = __builtin_amdgcn_mfma_f32_16x16x32_bf16(a[ks], bm,  accY[nt], 0, 0, 0);
      accG[nt] = __builtin_amdgcn_mfma_f32_16x16x32_bf16(a[ks], bg,  accG[nt], 0, 0, 0);
      accS[nt] = __builtin_amdgcn_mfma_f32_16x16x32_bf16(a[ks], bsw, accS[nt], 0, 0, 0);
    }
  }

#pragma unroll
  for (int nt = 0; nt < 4; ++nt) {
    int d = h + nt * 16 + l15;
    float bmv = bmn[d] + bme[d];
    float bgv = bgn[d] + bge[d];
#pragma unroll
    for (int r = 0; r < 4; ++r) {
      union { __hip_bfloat162 hh; unsigned u; } pck;
      pck.hh = __float22bfloat162_rn({accY[nt][r] + bmv,
                                      (accG[nt][r] + bgv) * NEG_LOG2E});
      sh[ng * 16 + q * 4 + r][d] = pck.u;
    }
  }
  __syncthreads();
#pragma unroll
  for (int it = 0; it < 4; ++it) {
    int idx = (it * 256 + t) * 4;
    int nl = idx >> 7, dd = idx & 127;
    int node = base_node + nl;
    if (node < n)
      *(uint4*)(YG + (size_t)node * D_DIM + dd) = *(const uint4*)&sh[nl][dd];
  }
  __syncthreads();

  float* shf = (float*)sh;
#pragma unroll
  for (int nt = 0; nt < 4; ++nt) {
    int d = h + nt * 16 + l15;
    float bsv = bs[d];
#pragma unroll
    for (int r = 0; r < 4; ++r)
      shf[(ng * 16 + q * 4 + r) * 132 + d] = sigmoid_fast(accS[nt][r] + bsv) + 0.5f;
  }
  __syncthreads();
#pragma unroll
  for (int it = 0; it < 4; ++it) {
    int idx = (it * 256 + t) * 4;
    int nl = idx >> 7, dd = idx & 127;
    int node = base_node + nl;
    if (node < n) {
      float4 xv = *(const float4*)(x + (size_t)node * D_DIM + dd);
      float4 bo = *(const float4*)(bias_other + dd);
      const float* sp = &shf[nl * 132 + dd];
      float4 o;
      o.x = sp[0] * xv.x + bo.x;
      o.y = sp[1] * xv.y + bo.y;
      o.z = sp[2] * xv.z + bo.z;
      o.w = sp[3] * xv.w + bo.w;
      *(float4*)(out_init + (size_t)node * D_DIM + dd) = o;
    }
  }
}

// Pass A: coarse partition, int4-vectorized. Block handles 4096 edges of each
// list; per-bucket contiguous runs reserved with one global atomicAdd.
// Entry = {src, ef_hi24|loc8}.
__global__ __launch_bounds__(256) void sort_a_kernel(
    const int* __restrict__ src_dt, const int* __restrict__ dst_dt, const float* __restrict__ ef_dt,
    const int* __restrict__ src_td, const int* __restrict__ dst_td, const float* __restrict__ ef_td,
    int* __restrict__ bcur, int2* __restrict__ eA, int nbt, int NB, int E) {
  __shared__ int lh[768];
  __shared__ int lcur[768];
  int t = threadIdx.x;
  lh[t] = 0; lh[t + 256] = 0; lh[t + 512] = 0;
  __syncthreads();
  int e0 = blockIdx.x * 4096;
  int e1 = min(E, e0 + 4096);
  const bool full = (e1 - e0 == 4096);
  if (full) {
#pragma unroll
    for (int k = 0; k < 4; ++k) {
      int b4 = e0 + (k * 256 + t) * 4;
      int4 d = *(const int4*)(dst_dt + b4);
      atomicAdd(&lh[d.x >> 6], 1); atomicAdd(&lh[d.y >> 6], 1);
      atomicAdd(&lh[d.z >> 6], 1); atomicAdd(&lh[d.w >> 6], 1);
      int4 d2 = *(const int4*)(dst_td + b4);
      atomicAdd(&lh[nbt + (d2.x >> 8)], 1); atomicAdd(&lh[nbt + (d2.y >> 8)], 1);
      atomicAdd(&lh[nbt + (d2.z >> 8)], 1); atomicAdd(&lh[nbt + (d2.w >> 8)], 1);
    }
  } else {
    for (int i = e0 + t; i < e1; i += 256) {
      atomicAdd(&lh[dst_dt[i] >> 6], 1);
      atomicAdd(&lh[nbt + (dst_td[i] >> 8)], 1);
    }
  }
  __syncthreads();
#pragma unroll
  for (int k = 0; k < 3; ++k) {
    int b = t + k * 256;
    int c = lh[b];
    if (b < NB && c) lcur[b] = atomicAdd(&bcur[b], c);
  }
  __syncthreads();
#define PUT_DT(ss, dd, ff) do { \
    int pos = atomicAdd(&lcur[(dd) >> 6], 1); \
    eA[pos] = make_int2((ss), (int)((__float_as_uint(ff) & 0xFFFFFF00u) | (unsigned)((dd) & 63))); \
  } while (0)
#define PUT_TD(ss, dd, ff) do { \
    int pos = atomicAdd(&lcur[nbt + ((dd) >> 8)], 1); \
    eA[pos] = make_int2((ss), (int)((__float_as_uint(ff) & 0xFFFFFF00u) | (unsigned)((dd) & 255))); \
  } while (0)
  if (full) {
#pragma unroll
    for (int k = 0; k < 4; ++k) {
      int b4 = e0 + (k * 256 + t) * 4;
      int4 s = *(const int4*)(src_dt + b4);
      int4 d = *(const int4*)(dst_dt + b4);
      float4 f = *(const float4*)(ef_dt + b4);
      PUT_DT(s.x, d.x, f.x); PUT_DT(s.y, d.y, f.y);
      PUT_DT(s.z, d.z, f.z); PUT_DT(s.w, d.w, f.w);
      s = *(const int4*)(src_td + b4);
      d = *(const int4*)(dst_td + b4);
      f = *(const float4*)(ef_td + b4);
      PUT_TD(s.x, d.x, f.x); PUT_TD(s.y, d.y, f.y);
      PUT_TD(s.z, d.z, f.z); PUT_TD(s.w, d.w, f.w);
    }
  } else {
    for (int i = e0 + t; i < e1; i += 256) {
      PUT_DT(src_dt[i], dst_dt[i], ef_dt[i]);
      PUT_TD(src_td[i], dst_td[i], ef_td[i]);
    }
  }
#undef PUT_DT
#undef PUT_TD
}

// Pass B: one block per bucket. 256-bin hist+scan; write final per-dst offsets;
// scatter entries within the bucket's contiguous (L2-resident) region.
__global__ __launch_bounds__(256) void sort_b_kernel(
    const int2* __restrict__ eA, const int* __restrict__ bbase,
    int* __restrict__ offsets, int2* __restrict__ eB,
    int nbt, int n_task, int n_tot) {
  __shared__ int lh[256], sc[256], lcur[256];
  int b = blockIdx.x, t = threadIdx.x;
  int base = bbase[b];
  int cnt = bbase[b + 1] - base;
  int c0, nloc;
  if (b < nbt) { c0 = b << 6; nloc = min(64, n_task - c0); }
  else { c0 = n_task + ((b - nbt) << 8); nloc = min(256, n_tot - c0); }
  lh[t] = 0; __syncthreads();
  for (int i = base + t; i < base + cnt; i += 256)
    atomicAdd(&lh[((unsigned)eA[i].y) & 255u], 1);
  __syncthreads();
  int v = lh[t];
  sc[t] = v; __syncthreads();
  for (int s = 1; s < 256; s <<= 1) {
    int u = (t >= s) ? sc[t - s] : 0;
    __syncthreads(); sc[t] += u; __syncthreads();
  }
  int ex = sc[t] - v;
  lcur[t] = base + ex;
  if (t < nloc) offsets[c0 + t] = base + ex;
  __syncthreads();
  for (int i = base + t; i < base + cnt; i += 256) {
    int2 e = eA[i];
    int pos = atomicAdd(&lcur[((unsigned)e.y) & 255u], 1);
    eB[pos] = e;
  }
}

// Combined gather, 2-stage software-pipelined: while batch k's VALU runs,
// batch k+1's 8 edata + 8 YG loads are in flight (named regs, rotate).
__device__ __forceinline__ void gs(float2& acc, int2 e, uint2 yv,
                                   float2 wme, float2 wge2) {
  float f = __int_as_float(e.y & (int)0xFFFFFF00);
  float g0 = __builtin_amdgcn_rcpf(1.0f + __builtin_amdgcn_exp2f(fmaf(f, wge2.x, bf_hi(yv.x)))) - 0.5f;
  float g1 = __builtin_amdgcn_rcpf(1.0f + __builtin_amdgcn_exp2f(fmaf(f, wge2.y, bf_hi(yv.y)))) - 0.5f;
  acc.x = fmaf(fmaf(f, wme.x, bf_lo(yv.x)), g0, acc.x);
  acc.y = fmaf(fmaf(f, wme.y, bf_lo(yv.y)), g1, acc.y);
}

__global__ __launch_bounds__(256) void gather_kernel(
    const unsigned* __restrict__ YG_dt, const unsigned* __restrict__ YG_td,
    const int* __restrict__ offsets, const int2* __restrict__ edata,
    const float* __restrict__ Wme_dt, const float* __restrict__ Wge_dt,
    const float* __restrict__ Wme_td, const float* __restrict__ Wge_td,
    float* __restrict__ out, int n_task, int n_data) {
  int w = (int)((blockIdx.x * 256u + threadIdx.x) >> 6);
  int lane = threadIdx.x & 63;
  if (w >= n_task + n_data) return;
  bool is_dt = w < n_task;
  const unsigned* YG = is_dt ? YG_dt : YG_td;
  const float* Wme = is_dt ? Wme_dt : Wme_td;
  const float* Wge = is_dt ? Wge_dt : Wge_td;
  size_t orow = is_dt ? (size_t)(n_data + w) : (size_t)(w - n_task);
  int beg = __builtin_amdgcn_readfirstlane(offsets[w]);
  int end = __builtin_amdgcn_readfirstlane(offsets[w + 1]);
  float2 wme = *(const float2*)(Wme + 2 * lane);
  float2 wge = *(const float2*)(Wge + 2 * lane);
  float2 wge2 = {wge.x * NEG_LOG2E, wge.y * NEG_LOG2E};
  float* op = out + orow * D_DIM + 2 * lane;
  float2 acc0 = *(const float2*)op;
  float2 acc1 = {0.0f, 0.0f}, acc2 = {0.0f, 0.0f}, acc3 = {0.0f, 0.0f};
  int p = beg;
#define YGLD(e) (*(const uint2*)(YG + (size_t)(e).x * D_DIM + 2 * lane))
  if (p + 8 <= end) {
    int2 e0 = edata[p],     e1 = edata[p + 1], e2 = edata[p + 2], e3 = edata[p + 3];
    int2 e4 = edata[p + 4], e5 = edata[p + 5], e6 = edata[p + 6], e7 = edata[p + 7];
    uint2 y0 = YGLD(e0), y1 = YGLD(e1), y2 = YGLD(e2), y3 = YGLD(e3);
    uint2 y4 = YGLD(e4), y5 = YGLD(e5), y6 = YGLD(e6), y7 = YGLD(e7);
    p += 8;
    for (; p + 8 <= end; p += 8) {
      int2 f0 = edata[p],     f1 = edata[p + 1], f2 = edata[p + 2], f3 = edata[p + 3];
      int2 f4 = edata[p + 4], f5 = edata[p + 5], f6 = edata[p + 6], f7 = edata[p + 7];
      uint2 z0 = YGLD(f0), z1 = YGLD(f1), z2 = YGLD(f2), z3 = YGLD(f3);
      uint2 z4 = YGLD(f4), z5 = YGLD(f5), z6 = YGLD(f6), z7 = YGLD(f7);
      gs(acc0, e0, y0, wme, wge2); gs(acc1, e1, y1, wme, wge2);
      gs(acc2, e2, y2, wme, wge2); gs(acc3, e3, y3, wme, wge2);
      gs(acc0, e4, y4, wme, wge2); gs(acc1, e5, y5, wme, wge2);
      gs(acc2, e6, y6, wme, wge2); gs(acc3, e7, y7, wme, wge2);
      e0 = f0; e1 = f1; e2 = f2; e3 = f3; e4 = f4; e5 = f5; e6 = f6; e7 = f7;
      y0 = z0; y1 = z1; y2 = z2; y3 = z3; y4 = z4; y5 = z5; y6 = z6; y7 = z7;
    }
    gs(acc0, e0, y0, wme, wge2); gs(acc1, e1, y1, wme, wge2);
    gs(acc2, e2, y2, wme, wge2); gs(acc3, e3, y3, wme, wge2);
    gs(acc0, e4, y4, wme, wge2); gs(acc1, e5, y5, wme, wge2);
    gs(acc2, e6, y6, wme, wge2); gs(acc3, e7, y7, wme, wge2);
  }
  for (; p < end; ++p) {
    int2 et = edata[p];
    uint2 yt = YGLD(et);
    gs(acc0, et, yt, wme, wge2);
  }
#undef YGLD
  acc0.x = fmaxf(acc0.x + acc1.x + acc2.x + acc3.x, 0.0f);
  acc0.y = fmaxf(acc0.y + acc1.y + acc2.y + acc3.y, 0.0f);
  *(float2*)op = acc0;
}

extern "C" void kernel_launch(void* const* d_in, const int* in_sizes, int n_in,
                              void* d_out, int out_size, void* d_ws, size_t ws_size,
                              hipStream_t stream) {
  const float* x_data  = (const float*)d_in[0];
  const float* x_task  = (const float*)d_in[1];
  const int*   src_dt  = (const int*)d_in[2];
  const int*   dst_dt  = (const int*)d_in[3];
  const float* ef_dt   = (const float*)d_in[4];
  const int*   src_td  = (const int*)d_in[5];
  const int*   dst_td  = (const int*)d_in[6];
  const float* ef_td   = (const float*)d_in[7];
  const float* Wmn_dt  = (const float*)d_in[8];
  const float* bmn_dt  = (const float*)d_in[9];
  const float* Wme_dt  = (const float*)d_in[10];
  const float* bme_dt  = (const float*)d_in[11];
  const float* Wgn_dt  = (const float*)d_in[12];
  const float* bgn_dt  = (const float*)d_in[13];
  const float* Wge_dt  = (const float*)d_in[14];
  const float* bge_dt  = (const float*)d_in[15];
  const float* bias_dt = (const float*)d_in[16];
  const float* Wmn_td  = (const float*)d_in[17];
  const float* bmn_td  = (const float*)d_in[18];
  const float* Wme_td  = (const float*)d_in[19];
  const float* bme_td  = (const float*)d_in[20];
  const float* Wgn_td  = (const float*)d_in[21];
  const float* bgn_td  = (const float*)d_in[22];
  const float* Wge_td  = (const float*)d_in[23];
  const float* bge_td  = (const float*)d_in[24];
  const float* bias_td = (const float*)d_in[25];
  const float* Ws_data = (const float*)d_in[26];
  const float* bs_data = (const float*)d_in[27];
  const float* Ws_task = (const float*)d_in[28];
  const float* bs_task = (const float*)d_in[29];
  float* out = (float*)d_out;

  const int N_DATA = in_sizes[0] / D_DIM;   // 100000
  const int N_TASK = in_sizes[1] / D_DIM;   // 20000
  const int E = in_sizes[2];                // 1000000
  const int N_TOT = N_TASK + N_DATA;
  const int NBT = (N_TASK + 63) >> 6;       // 313 task buckets (64 dsts each)
  const int NBD = (N_DATA + 255) >> 8;      // 391 data buckets (256 dsts each)
  const int NB = NBT + NBD;                 // 704
  const int GD = (N_DATA + 31) / 32;
  const int GT = (N_TASK + 31) / 32;

  char* ws = (char*)d_ws;
  size_t off = 0;
  auto alloc = [&](size_t bytes) { void* p = ws + off; off += (bytes + 255) & ~(size_t)255; return p; };
  unsigned int* YG_dt = (unsigned int*)alloc((size_t)N_DATA * D_DIM * 4);
  unsigned int* YG_td = (unsigned int*)alloc((size_t)N_TASK * D_DIM * 4);
  int2* eA     = (int2*)alloc((size_t)2 * E * 8);
  int2* eB     = (int2*)alloc((size_t)2 * E * 8);
  int*  offs   = (int*)alloc((size_t)(N_TOT + 1) * 4);
  int*  ghist  = (int*)alloc(1024 * 4);     // 768 hist + done counter
  int*  bbase  = (int*)alloc(768 * 4);
  int*  bcur   = (int*)alloc(768 * 4);
  short* Wb    = (short*)alloc((size_t)6 * 16384 * 2);
  (void)ws_size; (void)n_in; (void)out_size;

  hipMemsetAsync(ghist, 0, 1024 * 4, stream);

  fused_pre_kernel<<<256, 256, 0, stream>>>(
      Wmn_dt, Wgn_dt, Ws_data, Wmn_td, Wgn_td, Ws_task, Wb,
      dst_dt, dst_td, ghist, ghist + 768, bbase, bcur, offs,
      NBT, NB, E, N_TOT);

  node_mfma_all<<<GD + GT, 256, 0, stream>>>(
      x_data, x_task, Wb,
      bmn_dt, bme_dt, bgn_dt, bge_dt,
      bmn_td, bme_td, bgn_td, bge_td,
      bs_data, bs_task, bias_dt, bias_td,
      YG_dt, YG_td, out, N_DATA, N_TASK, GD);

  sort_a_kernel<<<(E + 4095) / 4096, 256, 0, stream>>>(
      src_dt, dst_dt, ef_dt, src_td, dst_td, ef_td, bcur, eA, NBT, NB, E);
  sort_b_kernel<<<NB, 256, 0, stream>>>(eA, bbase, offs, eB, NBT, N_TASK, N_TOT);

  gather_kernel<<<(N_TOT + 3) / 4, 256, 0, stream>>>(
      YG_dt, YG_td, offs, eB, Wme_dt, Wge_dt, Wme_td, Wge_td, out, N_TASK, N_DATA);
}